// Round 1
// baseline (341.426 us; speedup 1.0000x reference)
//
#include <hip/hip_runtime.h>
#include <hip/hip_bf16.h>
#include <stdint.h>

#define T_SEQ 2048
#define DIMSZ 1024
#define NH    16
#define HDIM  64
#define NBATCH 2
#define ATT_SCALE 0.12f

typedef __attribute__((ext_vector_type(8))) __bf16 bf16x8;
typedef __attribute__((ext_vector_type(4))) float f32x4;

#define GLOAD_LDS16(gp, lp)                                                            \
  __builtin_amdgcn_global_load_lds((const __attribute__((address_space(1))) void*)(gp),\
                                   (__attribute__((address_space(3))) void*)(lp),      \
                                   16, 0, 0)

__device__ __forceinline__ ushort f2bf(float f) {
  union { float f; uint32_t u; } v; v.f = f;
  uint32_t u = v.u;
  uint32_t r = (u + 0x7FFFu + ((u >> 16) & 1u)) >> 16;
  return (ushort)r;
}

// ---------------- f32 -> bf16 convert (vectorized) ----------------
__global__ __launch_bounds__(256) void conv_bf16_k(const float* __restrict__ in,
                                                   ushort* __restrict__ out, int n) {
  int i = (blockIdx.x * 256 + threadIdx.x) * 4;
  if (i >= n) return;
  float4 v = *(const float4*)(in + i);
  ushort4 o;
  o.x = f2bf(v.x); o.y = f2bf(v.y); o.z = f2bf(v.z); o.w = f2bf(v.w);
  *(ushort4*)(out + i) = o;
}

// ---------------- RoPE tables: cos/sin (T x 32) ----------------
__global__ __launch_bounds__(256) void rope_tab_k(float* __restrict__ ctab,
                                                  float* __restrict__ stab) {
  int idx = blockIdx.x * 256 + threadIdx.x;  // t*32 + j
  if (idx >= T_SEQ * 32) return;
  int j = idx & 31, t = idx >> 5;
  float c = 1.f, s = 0.f;
  if (j < 16) {
    float inv = powf(1024.0f, -(float)j / 15.0f);  // (1/1024)^(j/15)
    float th = (float)t * inv;
    c = cosf(th);
    s = sinf(th);
  }
  ctab[idx] = c;
  stab[idx] = s;
}

// ---------------- bf16 GEMM: C(MxN) = A(MxK) * Bt(NxK)^T, f32 out ----------------
#define BM 128
#define BN 128
#define BKS 64

__global__ __launch_bounds__(256) void gemm_bt_k(const ushort* __restrict__ A,
                                                 const ushort* __restrict__ Bt,
                                                 float* __restrict__ C,
                                                 int M, int N, int K) {
  __shared__ __align__(16) ushort As[BM * BKS];
  __shared__ __align__(16) ushort Bs[BN * BKS];
  int tid = threadIdx.x;
  int wave = tid >> 6, lane = tid & 63;
  int lr = lane & 15, lg = lane >> 4;
  int m0 = blockIdx.x * BM, n0 = blockIdx.y * BN;
  int wm = (wave >> 1) * 64, wn = (wave & 1) * 64;

  f32x4 acc[4][4];
  for (int m = 0; m < 4; ++m)
    for (int n = 0; n < 4; ++n)
      acc[m][n] = (f32x4){0.f, 0.f, 0.f, 0.f};

  for (int k0 = 0; k0 < K; k0 += BKS) {
#pragma unroll
    for (int it = 0; it < 4; ++it) {
      int idx = it * 256 + tid;        // 16B chunk id, 1024 total
      int row = idx >> 3;              // 8 chunks per 64-elem row
      int col = (idx & 7) * 8;
      GLOAD_LDS16(A + (size_t)(m0 + row) * K + k0 + col, &As[idx * 8]);
      GLOAD_LDS16(Bt + (size_t)(n0 + row) * K + k0 + col, &Bs[idx * 8]);
    }
    __syncthreads();
#pragma unroll
    for (int kk = 0; kk < 2; ++kk) {
      bf16x8 af[4], bf[4];
#pragma unroll
      for (int m = 0; m < 4; ++m)
        af[m] = *(const bf16x8*)&As[(wm + m * 16 + lr) * BKS + kk * 32 + lg * 8];
#pragma unroll
      for (int n = 0; n < 4; ++n)
        bf[n] = *(const bf16x8*)&Bs[(wn + n * 16 + lr) * BKS + kk * 32 + lg * 8];
#pragma unroll
      for (int m = 0; m < 4; ++m)
#pragma unroll
        for (int n = 0; n < 4; ++n)
          acc[m][n] = __builtin_amdgcn_mfma_f32_16x16x32_bf16(af[m], bf[n], acc[m][n], 0, 0, 0);
    }
    __syncthreads();
  }
#pragma unroll
  for (int m = 0; m < 4; ++m)
#pragma unroll
    for (int n = 0; n < 4; ++n)
#pragma unroll
      for (int r = 0; r < 4; ++r) {
        int row = m0 + wm + m * 16 + lg * 4 + r;
        int col = n0 + wn + n * 16 + lr;
        C[(size_t)row * N + col] = acc[m][n][r];
      }
}

// ---------------- per-(b,t,h): RMSNorm + RoPE + v-mix ----------------
__global__ __launch_bounds__(256) void qkv_post_k(const float* __restrict__ QKVf,
                                                  const float* __restrict__ ve,
                                                  const float* __restrict__ lam,
                                                  const float* __restrict__ ctab,
                                                  const float* __restrict__ stab,
                                                  ushort* __restrict__ Qb,
                                                  ushort* __restrict__ Kb,
                                                  ushort* __restrict__ Vt) {
  int idx = blockIdx.x * 4 + (threadIdx.x >> 6);  // (b*T + t)*NH + h
  int lane = threadIdx.x & 63;
  int h = idx & (NH - 1);
  int bt = idx >> 4;
  int t = bt & (T_SEQ - 1);
  int b = bt >> 11;

  const float* base = QKVf + (size_t)bt * 3072 + h * HDIM + lane;
  float qv = base[0];
  float kv = base[1024];
  float vv = base[2048];

  float sq = qv * qv, sk = kv * kv, sv = vv * vv;
#pragma unroll
  for (int off = 1; off < 64; off <<= 1) {
    sq += __shfl_xor(sq, off);
    sk += __shfl_xor(sk, off);
    sv += __shfl_xor(sv, off);
  }
  qv *= rsqrtf(sq * (1.0f / 64.0f) + 1e-6f);
  kv *= rsqrtf(sk * (1.0f / 64.0f) + 1e-6f);
  vv *= rsqrtf(sv * (1.0f / 64.0f) + 1e-6f);

  int j = lane & 31;
  float c = ctab[t * 32 + j];
  float s = stab[t * 32 + j];
  float qo = __shfl_xor(qv, 32);
  float ko = __shfl_xor(kv, 32);
  float q2 = (lane < 32) ? (qv * c + qo * s) : (qv * c - qo * s);
  float k2 = (lane < 32) ? (kv * c + ko * s) : (kv * c - ko * s);
  float v2 = lam[0] * vv + lam[1] * ve[(size_t)bt * DIMSZ + h * HDIM + lane];

  int bh = b * NH + h;
  Qb[((size_t)bh * T_SEQ + t) * HDIM + lane] = f2bf(q2);
  Kb[((size_t)bh * T_SEQ + t) * HDIM + lane] = f2bf(k2);
  Vt[((size_t)bh * HDIM + lane) * T_SEQ + t] = f2bf(v2);
}

// ---------------- flash attention ----------------
// grid (qb=32, bh=32), 256 thr (4 waves), wave owns 16 q-rows; KV blocks of 64.
__global__ __launch_bounds__(256) void attn_k(const ushort* __restrict__ Q,
                                              const ushort* __restrict__ K,
                                              const ushort* __restrict__ Vt,
                                              ushort* __restrict__ Y) {
  int qb = blockIdx.x;
  int bh = blockIdx.y;
  int wave = threadIdx.x >> 6, lane = threadIdx.x & 63;
  int lr = lane & 15, lg = lane >> 4;
  int b = bh >> 4, h = bh & 15;

  __shared__ __align__(16) ushort Plds[4][16][72];  // pad 72 halves = 144B rows

  int r0 = qb * 64 + wave * 16;
  const ushort* Qbase = Q + ((size_t)bh * T_SEQ + r0) * HDIM;
  bf16x8 aq[2];
#pragma unroll
  for (int kk = 0; kk < 2; ++kk)
    aq[kk] = *(const bf16x8*)(Qbase + (size_t)lr * HDIM + kk * 32 + lg * 8);

  f32x4 o[4];
#pragma unroll
  for (int n = 0; n < 4; ++n) o[n] = (f32x4){0.f, 0.f, 0.f, 0.f};
  float mrow[4] = {-1e30f, -1e30f, -1e30f, -1e30f};
  float lrow[4] = {0.f, 0.f, 0.f, 0.f};

  int nkv = qb + 1;
  for (int kb = 0; kb < nkv; ++kb) {
    int s0 = kb * 64;
    const ushort* Kbase = K + ((size_t)bh * T_SEQ + s0) * HDIM;
    f32x4 s[4];
#pragma unroll
    for (int n = 0; n < 4; ++n) {
      f32x4 a = (f32x4){0.f, 0.f, 0.f, 0.f};
#pragma unroll
      for (int kk = 0; kk < 2; ++kk) {
        bf16x8 bk = *(const bf16x8*)(Kbase + (size_t)(n * 16 + lr) * HDIM + kk * 32 + lg * 8);
        a = __builtin_amdgcn_mfma_f32_16x16x32_bf16(aq[kk], bk, a, 0, 0, 0);
      }
      s[n] = a;
    }
    bool diag = (kb == nkv - 1);
#pragma unroll
    for (int n = 0; n < 4; ++n)
#pragma unroll
      for (int r = 0; r < 4; ++r) {
        float v = s[n][r] * ATT_SCALE;
        if (diag) {
          int key = s0 + n * 16 + lr;
          int row = r0 + lg * 4 + r;
          if (key > row) v = -1e30f;
        }
        s[n][r] = v;
      }
    // row max over the 64 keys in this block
    float pm[4];
#pragma unroll
    for (int r = 0; r < 4; ++r)
      pm[r] = fmaxf(fmaxf(s[0][r], s[1][r]), fmaxf(s[2][r], s[3][r]));
#pragma unroll
    for (int off = 1; off < 16; off <<= 1)
#pragma unroll
      for (int r = 0; r < 4; ++r) pm[r] = fmaxf(pm[r], __shfl_xor(pm[r], off));
    float rs[4];
#pragma unroll
    for (int r = 0; r < 4; ++r) {
      float mnew = fmaxf(mrow[r], pm[r]);
      rs[r] = __expf(mrow[r] - mnew);
      mrow[r] = mnew;
      lrow[r] *= rs[r];
    }
    // probs -> lds (bf16), row-sums
    float psum[4] = {0.f, 0.f, 0.f, 0.f};
#pragma unroll
    for (int n = 0; n < 4; ++n)
#pragma unroll
      for (int r = 0; r < 4; ++r) {
        float p = __expf(s[n][r] - mrow[r]);
        psum[r] += p;
        Plds[wave][lg * 4 + r][n * 16 + lr] = f2bf(p);
      }
#pragma unroll
    for (int off = 1; off < 16; off <<= 1)
#pragma unroll
      for (int r = 0; r < 4; ++r) psum[r] += __shfl_xor(psum[r], off);
#pragma unroll
    for (int r = 0; r < 4; ++r) lrow[r] += psum[r];
    // rescale O
#pragma unroll
    for (int n = 0; n < 4; ++n)
#pragma unroll
      for (int r = 0; r < 4; ++r) o[n][r] *= rs[r];
    // PV
    const ushort* Vb = Vt + (size_t)bh * HDIM * T_SEQ + s0;
#pragma unroll
    for (int kk = 0; kk < 2; ++kk) {
      bf16x8 ap = *(const bf16x8*)&Plds[wave][lr][kk * 32 + lg * 8];
#pragma unroll
      for (int n = 0; n < 4; ++n) {
        bf16x8 bv = *(const bf16x8*)(Vb + (size_t)(n * 16 + lr) * T_SEQ + kk * 32 + lg * 8);
        o[n] = __builtin_amdgcn_mfma_f32_16x16x32_bf16(ap, bv, o[n], 0, 0, 0);
      }
    }
  }
  // epilogue: divide by row sums, write Y (B,T,DIM) bf16
#pragma unroll
  for (int n = 0; n < 4; ++n)
#pragma unroll
    for (int r = 0; r < 4; ++r) {
      int row = r0 + lg * 4 + r;
      float y = o[n][r] / lrow[r];
      Y[((size_t)b * T_SEQ + row) * DIMSZ + h * HDIM + n * 16 + lr] = f2bf(y);
    }
}

// ---------------- launch ----------------
extern "C" void kernel_launch(void* const* d_in, const int* in_sizes, int n_in,
                              void* d_out, int out_size, void* d_ws, size_t ws_size,
                              hipStream_t stream) {
  const float* x   = (const float*)d_in[0];
  const float* ve  = (const float*)d_in[1];
  const float* lam = (const float*)d_in[2];
  const float* w   = (const float*)d_in[4];  // (4, 1024, 1024)
  float* out = (float*)d_out;

  char* ws = (char*)d_ws;
  const size_t NTOK = (size_t)NBATCH * T_SEQ;          // 4096
  const size_t nX = NTOK * DIMSZ;                      // 4,194,304
  const size_t nW = 4ull * DIMSZ * DIMSZ;              // 4,194,304

  ushort* Xb   = (ushort*)(ws);                        // 8 MB
  ushort* Wb   = (ushort*)(ws + 8388608);              // 8 MB
  float*  QKVf = (float*)(ws + 16777216);              // 48 MB
  ushort* Qb   = (ushort*)(ws + 67108864);             // 8 MB
  ushort* Kb   = (ushort*)(ws + 75497472);             // 8 MB
  ushort* Vt   = (ushort*)(ws + 83886080);             // 8 MB
  ushort* Yb   = (ushort*)(ws + 92274688);             // 8 MB
  float*  ctab = (float*)(ws + 100663296);             // 256 KB
  float*  stab = (float*)(ws + 100925440);             // 256 KB

  conv_bf16_k<<<(int)(nX / 4 / 256), 256, 0, stream>>>(x, Xb, (int)nX);
  conv_bf16_k<<<(int)(nW / 4 / 256), 256, 0, stream>>>(w, Wb, (int)nW);
  rope_tab_k<<<(T_SEQ * 32) / 256, 256, 0, stream>>>(ctab, stab);

  // QKV: (4096 x 3072) = Xb (4096x1024) @ Wb[0:3072]^T
  gemm_bt_k<<<dim3(4096 / BM, 3072 / BN), 256, 0, stream>>>(Xb, Wb, QKVf, 4096, 3072, 1024);

  qkv_post_k<<<(int)(NTOK * NH / 4), 256, 0, stream>>>(QKVf, ve, lam, ctab, stab, Qb, Kb, Vt);

  attn_k<<<dim3(T_SEQ / 64, NBATCH * NH), 256, 0, stream>>>(Qb, Kb, Vt, Yb);

  // out: (4096 x 1024) = Yb @ W3^T, f32 straight to d_out
  gemm_bt_k<<<dim3(4096 / BM, 1024 / BN), 256, 0, stream>>>(Yb, Wb + 3ull * DIMSZ * DIMSZ, out, 4096, 1024, 1024);
}

// Round 2
// 233.252 us; speedup vs baseline: 1.4638x; 1.4638x over previous
//
#include <hip/hip_runtime.h>
#include <hip/hip_bf16.h>
#include <stdint.h>

#define T_SEQ 2048
#define DIMSZ 1024
#define NH    16
#define HDIM  64
#define NBATCH 2
#define ATT_SCALE 0.12f

typedef __attribute__((ext_vector_type(8))) __bf16 bf16x8;
typedef __attribute__((ext_vector_type(4))) float f32x4;

#define GLOAD_LDS16(gp, lp)                                                            \
  __builtin_amdgcn_global_load_lds((const __attribute__((address_space(1))) void*)(gp),\
                                   (__attribute__((address_space(3))) void*)(lp),      \
                                   16, 0, 0)

__device__ __forceinline__ ushort f2bf(float f) {
  union { float f; uint32_t u; } v; v.f = f;
  uint32_t u = v.u;
  uint32_t r = (u + 0x7FFFu + ((u >> 16) & 1u)) >> 16;
  return (ushort)r;
}

// ---------------- f32 -> bf16 convert (vectorized) ----------------
__global__ __launch_bounds__(256) void conv_bf16_k(const float* __restrict__ in,
                                                   ushort* __restrict__ out, int n) {
  int i = (blockIdx.x * 256 + threadIdx.x) * 4;
  if (i >= n) return;
  float4 v = *(const float4*)(in + i);
  ushort4 o;
  o.x = f2bf(v.x); o.y = f2bf(v.y); o.z = f2bf(v.z); o.w = f2bf(v.w);
  *(ushort4*)(out + i) = o;
}

// ---------------- RoPE tables: cos/sin (T x 32) ----------------
__global__ __launch_bounds__(256) void rope_tab_k(float* __restrict__ ctab,
                                                  float* __restrict__ stab) {
  int idx = blockIdx.x * 256 + threadIdx.x;  // t*32 + j
  if (idx >= T_SEQ * 32) return;
  int j = idx & 31, t = idx >> 5;
  float c = 1.f, s = 0.f;
  if (j < 16) {
    float inv = powf(1024.0f, -(float)j / 15.0f);  // (1/1024)^(j/15)
    float th = (float)t * inv;
    c = cosf(th);
    s = sinf(th);
  }
  ctab[idx] = c;
  stab[idx] = s;
}

// ---------------- bf16 GEMM: C(MxN) = A(MxK) * Bt(NxK)^T, f32 out ----------------
#define BM 128
#define BN 128
#define BKS 64

__global__ __launch_bounds__(256) void gemm_bt_k(const ushort* __restrict__ A,
                                                 const ushort* __restrict__ Bt,
                                                 float* __restrict__ C,
                                                 int M, int N, int K) {
  __shared__ __align__(16) ushort As[BM * BKS];
  __shared__ __align__(16) ushort Bs[BN * BKS];
  int tid = threadIdx.x;
  int wave = tid >> 6, lane = tid & 63;
  int lr = lane & 15, lg = lane >> 4;
  int m0 = blockIdx.x * BM, n0 = blockIdx.y * BN;
  int wm = (wave >> 1) * 64, wn = (wave & 1) * 64;

  f32x4 acc[4][4];
  for (int m = 0; m < 4; ++m)
    for (int n = 0; n < 4; ++n)
      acc[m][n] = (f32x4){0.f, 0.f, 0.f, 0.f};

  for (int k0 = 0; k0 < K; k0 += BKS) {
#pragma unroll
    for (int it = 0; it < 4; ++it) {
      int idx = it * 256 + tid;        // 16B chunk id, 1024 total
      int row = idx >> 3;              // 8 chunks per 64-elem row
      int col = (idx & 7) * 8;
      GLOAD_LDS16(A + (size_t)(m0 + row) * K + k0 + col, &As[idx * 8]);
      GLOAD_LDS16(Bt + (size_t)(n0 + row) * K + k0 + col, &Bs[idx * 8]);
    }
    __syncthreads();
#pragma unroll
    for (int kk = 0; kk < 2; ++kk) {
      bf16x8 af[4], bf[4];
#pragma unroll
      for (int m = 0; m < 4; ++m)
        af[m] = *(const bf16x8*)&As[(wm + m * 16 + lr) * BKS + kk * 32 + lg * 8];
#pragma unroll
      for (int n = 0; n < 4; ++n)
        bf[n] = *(const bf16x8*)&Bs[(wn + n * 16 + lr) * BKS + kk * 32 + lg * 8];
#pragma unroll
      for (int m = 0; m < 4; ++m)
#pragma unroll
        for (int n = 0; n < 4; ++n)
          acc[m][n] = __builtin_amdgcn_mfma_f32_16x16x32_bf16(af[m], bf[n], acc[m][n], 0, 0, 0);
    }
    __syncthreads();
  }
#pragma unroll
  for (int m = 0; m < 4; ++m)
#pragma unroll
    for (int n = 0; n < 4; ++n)
#pragma unroll
      for (int r = 0; r < 4; ++r) {
        int row = m0 + wm + m * 16 + lg * 4 + r;
        int col = n0 + wn + n * 16 + lr;
        C[(size_t)row * N + col] = acc[m][n][r];
      }
}

// ---------------- per-(b,t,h): RMSNorm + RoPE + v-mix ----------------
__global__ __launch_bounds__(256) void qkv_post_k(const float* __restrict__ QKVf,
                                                  const float* __restrict__ ve,
                                                  const float* __restrict__ lam,
                                                  const float* __restrict__ ctab,
                                                  const float* __restrict__ stab,
                                                  ushort* __restrict__ Qb,
                                                  ushort* __restrict__ Kb,
                                                  ushort* __restrict__ Vt) {
  int idx = blockIdx.x * 4 + (threadIdx.x >> 6);  // (b*T + t)*NH + h
  int lane = threadIdx.x & 63;
  int h = idx & (NH - 1);
  int bt = idx >> 4;
  int t = bt & (T_SEQ - 1);
  int b = bt >> 11;

  const float* base = QKVf + (size_t)bt * 3072 + h * HDIM + lane;
  float qv = base[0];
  float kv = base[1024];
  float vv = base[2048];

  float sq = qv * qv, sk = kv * kv, sv = vv * vv;
#pragma unroll
  for (int off = 1; off < 64; off <<= 1) {
    sq += __shfl_xor(sq, off);
    sk += __shfl_xor(sk, off);
    sv += __shfl_xor(sv, off);
  }
  qv *= rsqrtf(sq * (1.0f / 64.0f) + 1e-6f);
  kv *= rsqrtf(sk * (1.0f / 64.0f) + 1e-6f);
  vv *= rsqrtf(sv * (1.0f / 64.0f) + 1e-6f);

  int j = lane & 31;
  float c = ctab[t * 32 + j];
  float s = stab[t * 32 + j];
  float qo = __shfl_xor(qv, 32);
  float ko = __shfl_xor(kv, 32);
  float q2 = (lane < 32) ? (qv * c + qo * s) : (qv * c - qo * s);
  float k2 = (lane < 32) ? (kv * c + ko * s) : (kv * c - ko * s);
  float v2 = lam[0] * vv + lam[1] * ve[(size_t)bt * DIMSZ + h * HDIM + lane];

  int bh = b * NH + h;
  Qb[((size_t)bh * T_SEQ + t) * HDIM + lane] = f2bf(q2);
  Kb[((size_t)bh * T_SEQ + t) * HDIM + lane] = f2bf(k2);
  Vt[((size_t)bh * HDIM + lane) * T_SEQ + t] = f2bf(v2);
}

// ---------------- flash attention ----------------
// grid (pair=16, bh=32), 256 thr (4 waves). Each block does q-tile `pair` AND
// q-tile `31-pair` sequentially -> uniform 33 KV iterations per block.
// K frags software-pipelined one KV-block ahead; V frags issued before softmax.
__global__ __launch_bounds__(256, 2) void attn_k(const ushort* __restrict__ Q,
                                                 const ushort* __restrict__ K,
                                                 const ushort* __restrict__ Vt,
                                                 ushort* __restrict__ Y) {
  int pair = blockIdx.x;
  int bh = blockIdx.y;
  int wave = threadIdx.x >> 6, lane = threadIdx.x & 63;
  int lr = lane & 15, lg = lane >> 4;
  int b = bh >> 4, h = bh & 15;

  __shared__ __align__(16) ushort Plds[4][16][72];  // pad 72 halves = 144B rows

  const ushort* Kbh = K + (size_t)bh * T_SEQ * HDIM;
  const ushort* Vbh = Vt + (size_t)bh * HDIM * T_SEQ;

  for (int halfi = 0; halfi < 2; ++halfi) {
    int qb = halfi ? (31 - pair) : pair;
    int r0 = qb * 64 + wave * 16;
    int nkv = qb + 1;

    const ushort* Qbase = Q + ((size_t)bh * T_SEQ + r0) * HDIM;
    bf16x8 aq[2];
#pragma unroll
    for (int kk = 0; kk < 2; ++kk)
      aq[kk] = *(const bf16x8*)(Qbase + (size_t)lr * HDIM + kk * 32 + lg * 8);

    f32x4 o[4];
#pragma unroll
    for (int n = 0; n < 4; ++n) o[n] = (f32x4){0.f, 0.f, 0.f, 0.f};
    float mrow[4] = {-1e30f, -1e30f, -1e30f, -1e30f};
    float lrow[4] = {0.f, 0.f, 0.f, 0.f};

    // preload K block 0
    bf16x8 kc[8];
#pragma unroll
    for (int kk = 0; kk < 2; ++kk)
#pragma unroll
      for (int n = 0; n < 4; ++n)
        kc[kk * 4 + n] = *(const bf16x8*)(Kbh + (size_t)(n * 16 + lr) * HDIM + kk * 32 + lg * 8);

    for (int kb = 0; kb < nkv; ++kb) {
      int s0 = kb * 64;
      // QK^T from current K regs
      f32x4 s[4];
#pragma unroll
      for (int n = 0; n < 4; ++n) {
        f32x4 a = (f32x4){0.f, 0.f, 0.f, 0.f};
#pragma unroll
        for (int kk = 0; kk < 2; ++kk)
          a = __builtin_amdgcn_mfma_f32_16x16x32_bf16(aq[kk], kc[kk * 4 + n], a, 0, 0, 0);
        s[n] = a;
      }
      // prefetch next K block into the same regs (WAR after mfma issue; hidden
      // under softmax + PV below)
      if (kb + 1 < nkv) {
        const ushort* Kn = Kbh + (size_t)(s0 + 64) * HDIM;
#pragma unroll
        for (int kk = 0; kk < 2; ++kk)
#pragma unroll
          for (int n = 0; n < 4; ++n)
            kc[kk * 4 + n] = *(const bf16x8*)(Kn + (size_t)(n * 16 + lr) * HDIM + kk * 32 + lg * 8);
      }
      // issue V loads now; softmax hides their latency
      bf16x8 vv[8];
#pragma unroll
      for (int kk = 0; kk < 2; ++kk)
#pragma unroll
        for (int n = 0; n < 4; ++n)
          vv[kk * 4 + n] = *(const bf16x8*)(Vbh + (size_t)(n * 16 + lr) * T_SEQ + s0 + kk * 32 + lg * 8);

      bool diag = (kb == nkv - 1);
#pragma unroll
      for (int n = 0; n < 4; ++n)
#pragma unroll
        for (int r = 0; r < 4; ++r) {
          float v = s[n][r] * ATT_SCALE;
          if (diag) {
            int key = s0 + n * 16 + lr;
            int row = r0 + lg * 4 + r;
            if (key > row) v = -1e30f;
          }
          s[n][r] = v;
        }
      // row max over the 64 keys in this block
      float pm[4];
#pragma unroll
      for (int r = 0; r < 4; ++r)
        pm[r] = fmaxf(fmaxf(s[0][r], s[1][r]), fmaxf(s[2][r], s[3][r]));
#pragma unroll
      for (int off = 1; off < 16; off <<= 1)
#pragma unroll
        for (int r = 0; r < 4; ++r) pm[r] = fmaxf(pm[r], __shfl_xor(pm[r], off));
      float rs[4];
#pragma unroll
      for (int r = 0; r < 4; ++r) {
        float mnew = fmaxf(mrow[r], pm[r]);
        rs[r] = __expf(mrow[r] - mnew);
        mrow[r] = mnew;
        lrow[r] *= rs[r];
      }
      // probs -> lds (bf16), row-sums
      float psum[4] = {0.f, 0.f, 0.f, 0.f};
#pragma unroll
      for (int n = 0; n < 4; ++n)
#pragma unroll
        for (int r = 0; r < 4; ++r) {
          float p = __expf(s[n][r] - mrow[r]);
          psum[r] += p;
          Plds[wave][lg * 4 + r][n * 16 + lr] = f2bf(p);
        }
#pragma unroll
      for (int off = 1; off < 16; off <<= 1)
#pragma unroll
        for (int r = 0; r < 4; ++r) psum[r] += __shfl_xor(psum[r], off);
#pragma unroll
      for (int r = 0; r < 4; ++r) lrow[r] += psum[r];
      // rescale O
#pragma unroll
      for (int n = 0; n < 4; ++n)
#pragma unroll
        for (int r = 0; r < 4; ++r) o[n][r] *= rs[r];
      // PV
#pragma unroll
      for (int kk = 0; kk < 2; ++kk) {
        bf16x8 ap = *(const bf16x8*)&Plds[wave][lr][kk * 32 + lg * 8];
#pragma unroll
        for (int n = 0; n < 4; ++n)
          o[n] = __builtin_amdgcn_mfma_f32_16x16x32_bf16(ap, vv[kk * 4 + n], o[n], 0, 0, 0);
      }
    }
    // epilogue: divide by row sums, write Y (B,T,DIM) bf16
#pragma unroll
    for (int n = 0; n < 4; ++n)
#pragma unroll
      for (int r = 0; r < 4; ++r) {
        int row = r0 + lg * 4 + r;
        float y = o[n][r] / lrow[r];
        Y[((size_t)b * T_SEQ + row) * DIMSZ + h * HDIM + n * 16 + lr] = f2bf(y);
      }
  }
}

// ---------------- launch ----------------
extern "C" void kernel_launch(void* const* d_in, const int* in_sizes, int n_in,
                              void* d_out, int out_size, void* d_ws, size_t ws_size,
                              hipStream_t stream) {
  const float* x   = (const float*)d_in[0];
  const float* ve  = (const float*)d_in[1];
  const float* lam = (const float*)d_in[2];
  const float* w   = (const float*)d_in[4];  // (4, 1024, 1024)
  float* out = (float*)d_out;

  char* ws = (char*)d_ws;
  const size_t NTOK = (size_t)NBATCH * T_SEQ;          // 4096
  const size_t nX = NTOK * DIMSZ;                      // 4,194,304
  const size_t nW = 4ull * DIMSZ * DIMSZ;              // 4,194,304

  ushort* Xb   = (ushort*)(ws);                        // 8 MB
  ushort* Wb   = (ushort*)(ws + 8388608);              // 8 MB
  float*  QKVf = (float*)(ws + 16777216);              // 48 MB
  ushort* Qb   = (ushort*)(ws + 67108864);             // 8 MB
  ushort* Kb   = (ushort*)(ws + 75497472);             // 8 MB
  ushort* Vt   = (ushort*)(ws + 83886080);             // 8 MB
  ushort* Yb   = (ushort*)(ws + 92274688);             // 8 MB
  float*  ctab = (float*)(ws + 100663296);             // 256 KB
  float*  stab = (float*)(ws + 100925440);             // 256 KB

  conv_bf16_k<<<(int)(nX / 4 / 256), 256, 0, stream>>>(x, Xb, (int)nX);
  conv_bf16_k<<<(int)(nW / 4 / 256), 256, 0, stream>>>(w, Wb, (int)nW);
  rope_tab_k<<<(T_SEQ * 32) / 256, 256, 0, stream>>>(ctab, stab);

  // QKV: (4096 x 3072) = Xb (4096x1024) @ Wb[0:3072]^T
  gemm_bt_k<<<dim3(4096 / BM, 3072 / BN), 256, 0, stream>>>(Xb, Wb, QKVf, 4096, 3072, 1024);

  qkv_post_k<<<(int)(NTOK * NH / 4), 256, 0, stream>>>(QKVf, ve, lam, ctab, stab, Qb, Kb, Vt);

  attn_k<<<dim3(16, NBATCH * NH), 256, 0, stream>>>(Qb, Kb, Vt, Yb);

  // out: (4096 x 1024) = Yb @ W3^T, f32 straight to d_out
  gemm_bt_k<<<dim3(4096 / BM, 1024 / BN), 256, 0, stream>>>(Yb, Wb + 3ull * DIMSZ * DIMSZ, out, 4096, 1024, 1024);
}

// Round 3
// 232.500 us; speedup vs baseline: 1.4685x; 1.0032x over previous
//
#include <hip/hip_runtime.h>
#include <hip/hip_bf16.h>
#include <stdint.h>

#define T_SEQ 2048
#define DIMSZ 1024
#define NH    16
#define HDIM  64
#define NBATCH 2
#define ATT_SCALE 0.12f

typedef __attribute__((ext_vector_type(8))) __bf16 bf16x8;
typedef __attribute__((ext_vector_type(4))) float f32x4;

#define GLOAD_LDS16(gp, lp)                                                            \
  __builtin_amdgcn_global_load_lds((const __attribute__((address_space(1))) void*)(gp),\
                                   (__attribute__((address_space(3))) void*)(lp),      \
                                   16, 0, 0)

__device__ __forceinline__ ushort f2bf(float f) {
  union { float f; uint32_t u; } v; v.f = f;
  uint32_t u = v.u;
  uint32_t r = (u + 0x7FFFu + ((u >> 16) & 1u)) >> 16;
  return (ushort)r;
}

// ---------------- f32 -> bf16 convert (vectorized) ----------------
__global__ __launch_bounds__(256) void conv_bf16_k(const float* __restrict__ in,
                                                   ushort* __restrict__ out, int n) {
  int i = (blockIdx.x * 256 + threadIdx.x) * 4;
  if (i >= n) return;
  float4 v = *(const float4*)(in + i);
  ushort4 o;
  o.x = f2bf(v.x); o.y = f2bf(v.y); o.z = f2bf(v.z); o.w = f2bf(v.w);
  *(ushort4*)(out + i) = o;
}

// ---------------- RoPE tables: cos/sin (T x 32) ----------------
__global__ __launch_bounds__(256) void rope_tab_k(float* __restrict__ ctab,
                                                  float* __restrict__ stab) {
  int idx = blockIdx.x * 256 + threadIdx.x;  // t*32 + j
  if (idx >= T_SEQ * 32) return;
  int j = idx & 31, t = idx >> 5;
  float c = 1.f, s = 0.f;
  if (j < 16) {
    float inv = powf(1024.0f, -(float)j / 15.0f);  // (1/1024)^(j/15)
    float th = (float)t * inv;
    c = cosf(th);
    s = sinf(th);
  }
  ctab[idx] = c;
  stab[idx] = s;
}

// ---------------- bf16 GEMM: C(MxN) = A(MxK) * Bt(NxK)^T, f32 out ----------------
#define BM 128
#define BN 128
#define BKS 64

__global__ __launch_bounds__(256) void gemm_bt_k(const ushort* __restrict__ A,
                                                 const ushort* __restrict__ Bt,
                                                 float* __restrict__ C,
                                                 int M, int N, int K) {
  __shared__ __align__(16) ushort As[BM * BKS];
  __shared__ __align__(16) ushort Bs[BN * BKS];
  int tid = threadIdx.x;
  int wave = tid >> 6, lane = tid & 63;
  int lr = lane & 15, lg = lane >> 4;
  int m0 = blockIdx.x * BM, n0 = blockIdx.y * BN;
  int wm = (wave >> 1) * 64, wn = (wave & 1) * 64;

  f32x4 acc[4][4];
  for (int m = 0; m < 4; ++m)
    for (int n = 0; n < 4; ++n)
      acc[m][n] = (f32x4){0.f, 0.f, 0.f, 0.f};

  for (int k0 = 0; k0 < K; k0 += BKS) {
#pragma unroll
    for (int it = 0; it < 4; ++it) {
      int idx = it * 256 + tid;        // 16B chunk id, 1024 total
      int row = idx >> 3;              // 8 chunks per 64-elem row
      int col = (idx & 7) * 8;
      GLOAD_LDS16(A + (size_t)(m0 + row) * K + k0 + col, &As[idx * 8]);
      GLOAD_LDS16(Bt + (size_t)(n0 + row) * K + k0 + col, &Bs[idx * 8]);
    }
    __syncthreads();
#pragma unroll
    for (int kk = 0; kk < 2; ++kk) {
      bf16x8 af[4], bf[4];
#pragma unroll
      for (int m = 0; m < 4; ++m)
        af[m] = *(const bf16x8*)&As[(wm + m * 16 + lr) * BKS + kk * 32 + lg * 8];
#pragma unroll
      for (int n = 0; n < 4; ++n)
        bf[n] = *(const bf16x8*)&Bs[(wn + n * 16 + lr) * BKS + kk * 32 + lg * 8];
#pragma unroll
      for (int m = 0; m < 4; ++m)
#pragma unroll
        for (int n = 0; n < 4; ++n)
          acc[m][n] = __builtin_amdgcn_mfma_f32_16x16x32_bf16(af[m], bf[n], acc[m][n], 0, 0, 0);
    }
    __syncthreads();
  }
#pragma unroll
  for (int m = 0; m < 4; ++m)
#pragma unroll
    for (int n = 0; n < 4; ++n)
#pragma unroll
      for (int r = 0; r < 4; ++r) {
        int row = m0 + wm + m * 16 + lg * 4 + r;
        int col = n0 + wn + n * 16 + lr;
        C[(size_t)row * N + col] = acc[m][n][r];
      }
}

// ---------------- per-(b,t,h): RMSNorm + RoPE + v-mix ----------------
// Q gets ATT_SCALE * log2(e) folded in so attention softmax runs in exp2 domain.
__global__ __launch_bounds__(256) void qkv_post_k(const float* __restrict__ QKVf,
                                                  const float* __restrict__ ve,
                                                  const float* __restrict__ lam,
                                                  const float* __restrict__ ctab,
                                                  const float* __restrict__ stab,
                                                  ushort* __restrict__ Qb,
                                                  ushort* __restrict__ Kb,
                                                  ushort* __restrict__ Vt) {
  int idx = blockIdx.x * 4 + (threadIdx.x >> 6);  // (b*T + t)*NH + h
  int lane = threadIdx.x & 63;
  int h = idx & (NH - 1);
  int bt = idx >> 4;
  int t = bt & (T_SEQ - 1);
  int b = bt >> 11;

  const float* base = QKVf + (size_t)bt * 3072 + h * HDIM + lane;
  float qv = base[0];
  float kv = base[1024];
  float vv = base[2048];

  float sq = qv * qv, sk = kv * kv, sv = vv * vv;
#pragma unroll
  for (int off = 1; off < 64; off <<= 1) {
    sq += __shfl_xor(sq, off);
    sk += __shfl_xor(sk, off);
    sv += __shfl_xor(sv, off);
  }
  qv *= rsqrtf(sq * (1.0f / 64.0f) + 1e-6f);
  kv *= rsqrtf(sk * (1.0f / 64.0f) + 1e-6f);
  vv *= rsqrtf(sv * (1.0f / 64.0f) + 1e-6f);

  int j = lane & 31;
  float c = ctab[t * 32 + j];
  float s = stab[t * 32 + j];
  float qo = __shfl_xor(qv, 32);
  float ko = __shfl_xor(kv, 32);
  float q2 = (lane < 32) ? (qv * c + qo * s) : (qv * c - qo * s);
  float k2 = (lane < 32) ? (kv * c + ko * s) : (kv * c - ko * s);
  float v2 = lam[0] * vv + lam[1] * ve[(size_t)bt * DIMSZ + h * HDIM + lane];

  q2 *= ATT_SCALE * 1.4426950408889634f;  // fold scale + log2(e) for exp2-domain softmax

  int bh = b * NH + h;
  Qb[((size_t)bh * T_SEQ + t) * HDIM + lane] = f2bf(q2);
  Kb[((size_t)bh * T_SEQ + t) * HDIM + lane] = f2bf(k2);
  Vt[((size_t)bh * HDIM + lane) * T_SEQ + t] = f2bf(v2);
}

// ---------------- flash attention (swapped-operand, lane-local softmax) ----------------
// grid (bh=32, pair=16) -> linear%8 = bh%8, so all pair-blocks of a head share one
// XCD's L2 (512KB K+V per head, 4 heads -> 2MB per 4MB L2).
// Per wave: 16 q-rows; q-row = lane&15 EVERYWHERE (S^T = mfma(K,Q), O^T = mfma(V^T,P)).
// Softmax stats are lane-local: 15 in-lane ops + 2 shuffles per reduce.
__global__ __launch_bounds__(256, 2) void attn_k(const ushort* __restrict__ Q,
                                                 const ushort* __restrict__ K,
                                                 const ushort* __restrict__ Vt,
                                                 ushort* __restrict__ Y) {
  int bh = blockIdx.x;    // 0..31
  int pair = blockIdx.y;  // 0..15
  int wave = threadIdx.x >> 6, lane = threadIdx.x & 63;
  int lr = lane & 15, lg = lane >> 4;
  int b = bh >> 4, h = bh & 15;

  __shared__ __align__(16) ushort Plds[4][16][72];  // per-wave P tile, 144B rows (2-way banks)

  const ushort* Kbh = K + (size_t)bh * T_SEQ * HDIM;
  const ushort* Vbh = Vt + (size_t)bh * HDIM * T_SEQ;

  for (int halfi = 0; halfi < 2; ++halfi) {
    int qb = halfi ? (31 - pair) : pair;
    int r0 = qb * 64 + wave * 16;
    int nkv = qb + 1;

    const ushort* Qbase = Q + ((size_t)bh * T_SEQ + r0) * HDIM;
    bf16x8 aq[2];
#pragma unroll
    for (int kk = 0; kk < 2; ++kk)
      aq[kk] = *(const bf16x8*)(Qbase + (size_t)lr * HDIM + kk * 32 + lg * 8);

    f32x4 o[4];
#pragma unroll
    for (int n = 0; n < 4; ++n) o[n] = (f32x4){0.f, 0.f, 0.f, 0.f};
    float mrow = -1e30f;  // per-lane: stats for q-row r0+lr (exp2 domain)
    float lrow = 0.f;

    // preload K block 0
    bf16x8 kc[8];
#pragma unroll
    for (int kk = 0; kk < 2; ++kk)
#pragma unroll
      for (int n = 0; n < 4; ++n)
        kc[kk * 4 + n] = *(const bf16x8*)(Kbh + (size_t)(n * 16 + lr) * HDIM + kk * 32 + lg * 8);

    for (int kb = 0; kb < nkv; ++kb) {
      int s0 = kb * 64;
      // S^T = K . Q^T : lane holds S[q=r0+lr][key = s0 + n*16 + lg*4 + r]
      f32x4 s[4];
#pragma unroll
      for (int n = 0; n < 4; ++n) {
        f32x4 a = (f32x4){0.f, 0.f, 0.f, 0.f};
#pragma unroll
        for (int kk = 0; kk < 2; ++kk)
          a = __builtin_amdgcn_mfma_f32_16x16x32_bf16(kc[kk * 4 + n], aq[kk], a, 0, 0, 0);
        s[n] = a;
      }
      // prefetch next K block (WAR-safe; hidden under softmax + PV)
      if (kb + 1 < nkv) {
        const ushort* Kn = Kbh + (size_t)(s0 + 64) * HDIM;
#pragma unroll
        for (int kk = 0; kk < 2; ++kk)
#pragma unroll
          for (int n = 0; n < 4; ++n)
            kc[kk * 4 + n] = *(const bf16x8*)(Kn + (size_t)(n * 16 + lr) * HDIM + kk * 32 + lg * 8);
      }
      // issue V loads now; softmax hides their latency
      bf16x8 vv[8];
#pragma unroll
      for (int kk = 0; kk < 2; ++kk)
#pragma unroll
        for (int n = 0; n < 4; ++n)
          vv[kk * 4 + n] = *(const bf16x8*)(Vbh + (size_t)(n * 16 + lr) * T_SEQ + s0 + kk * 32 + lg * 8);

      // causal mask on the diagonal block (scores already scaled via Q)
      if (kb == nkv - 1) {
        int qrow = r0 + lr;
#pragma unroll
        for (int n = 0; n < 4; ++n)
#pragma unroll
          for (int r = 0; r < 4; ++r) {
            int key = s0 + n * 16 + lg * 4 + r;
            if (key > qrow) s[n][r] = -1e30f;
          }
      }
      // row max: 15 in-lane + 2 shuffles (over lg groups)
      float pm = fmaxf(fmaxf(fmaxf(s[0][0], s[0][1]), fmaxf(s[0][2], s[0][3])),
                       fmaxf(fmaxf(s[1][0], s[1][1]), fmaxf(s[1][2], s[1][3])));
      pm = fmaxf(pm, fmaxf(fmaxf(fmaxf(s[2][0], s[2][1]), fmaxf(s[2][2], s[2][3])),
                           fmaxf(fmaxf(s[3][0], s[3][1]), fmaxf(s[3][2], s[3][3]))));
      pm = fmaxf(pm, __shfl_xor(pm, 16));
      pm = fmaxf(pm, __shfl_xor(pm, 32));
      float mnew = fmaxf(mrow, pm);
      float rs = exp2f(mrow - mnew);
      mrow = mnew;
      // P = exp2(S - m); in-lane row sum
      float p[4][4];
      float psum = 0.f;
#pragma unroll
      for (int n = 0; n < 4; ++n)
#pragma unroll
        for (int r = 0; r < 4; ++r) {
          float pv = exp2f(s[n][r] - mrow);
          p[n][r] = pv;
          psum += pv;
        }
      psum += __shfl_xor(psum, 16);
      psum += __shfl_xor(psum, 32);
      lrow = lrow * rs + psum;
      // rescale O (lane-local rs)
#pragma unroll
      for (int n = 0; n < 4; ++n)
#pragma unroll
        for (int r = 0; r < 4; ++r) o[n][r] *= rs;
      // P -> LDS as bf16: row q=lr, cols key; 4x ds_write_b64
#pragma unroll
      for (int n = 0; n < 4; ++n) {
        uint2 w;
        w.x = (uint32_t)f2bf(p[n][0]) | ((uint32_t)f2bf(p[n][1]) << 16);
        w.y = (uint32_t)f2bf(p[n][2]) | ((uint32_t)f2bf(p[n][3]) << 16);
        *(uint2*)&Plds[wave][lr][n * 16 + lg * 4] = w;
      }
      // PV: O^T += V^T . P^T  (A = V^T frag, B = P frag read row-wise)
#pragma unroll
      for (int kk = 0; kk < 2; ++kk) {
        bf16x8 ap = *(const bf16x8*)&Plds[wave][lr][kk * 32 + lg * 8];
#pragma unroll
        for (int n = 0; n < 4; ++n)
          o[n] = __builtin_amdgcn_mfma_f32_16x16x32_bf16(vv[kk * 4 + n], ap, o[n], 0, 0, 0);
      }
    }
    // epilogue: lane holds O[q=r0+lr][d = n*16 + lg*4 + r]; divide by lane-local sum
    float inv = 1.0f / lrow;
    int row = r0 + lr;
#pragma unroll
    for (int n = 0; n < 4; ++n) {
      uint2 w;
      w.x = (uint32_t)f2bf(o[n][0] * inv) | ((uint32_t)f2bf(o[n][1] * inv) << 16);
      w.y = (uint32_t)f2bf(o[n][2] * inv) | ((uint32_t)f2bf(o[n][3] * inv) << 16);
      *(uint2*)&Y[((size_t)b * T_SEQ + row) * DIMSZ + h * HDIM + n * 16 + lg * 4] = w;
    }
  }
}

// ---------------- launch ----------------
extern "C" void kernel_launch(void* const* d_in, const int* in_sizes, int n_in,
                              void* d_out, int out_size, void* d_ws, size_t ws_size,
                              hipStream_t stream) {
  const float* x   = (const float*)d_in[0];
  const float* ve  = (const float*)d_in[1];
  const float* lam = (const float*)d_in[2];
  const float* w   = (const float*)d_in[4];  // (4, 1024, 1024)
  float* out = (float*)d_out;

  char* ws = (char*)d_ws;
  const size_t NTOK = (size_t)NBATCH * T_SEQ;          // 4096
  const size_t nX = NTOK * DIMSZ;                      // 4,194,304
  const size_t nW = 4ull * DIMSZ * DIMSZ;              // 4,194,304

  ushort* Xb   = (ushort*)(ws);                        // 8 MB
  ushort* Wb   = (ushort*)(ws + 8388608);              // 8 MB
  float*  QKVf = (float*)(ws + 16777216);              // 48 MB
  ushort* Qb   = (ushort*)(ws + 67108864);             // 8 MB
  ushort* Kb   = (ushort*)(ws + 75497472);             // 8 MB
  ushort* Vt   = (ushort*)(ws + 83886080);             // 8 MB
  ushort* Yb   = (ushort*)(ws + 92274688);             // 8 MB
  float*  ctab = (float*)(ws + 100663296);             // 256 KB
  float*  stab = (float*)(ws + 100925440);             // 256 KB

  conv_bf16_k<<<(int)(nX / 4 / 256), 256, 0, stream>>>(x, Xb, (int)nX);
  conv_bf16_k<<<(int)(nW / 4 / 256), 256, 0, stream>>>(w, Wb, (int)nW);
  rope_tab_k<<<(T_SEQ * 32) / 256, 256, 0, stream>>>(ctab, stab);

  // QKV: (4096 x 3072) = Xb (4096x1024) @ Wb[0:3072]^T
  gemm_bt_k<<<dim3(4096 / BM, 3072 / BN), 256, 0, stream>>>(Xb, Wb, QKVf, 4096, 3072, 1024);

  qkv_post_k<<<(int)(NTOK * NH / 4), 256, 0, stream>>>(QKVf, ve, lam, ctab, stab, Qb, Kb, Vt);

  attn_k<<<dim3(NBATCH * NH, 16), 256, 0, stream>>>(Qb, Kb, Vt, Yb);

  // out: (4096 x 1024) = Yb @ W3^T, f32 straight to d_out
  gemm_bt_k<<<dim3(4096 / BM, 1024 / BN), 256, 0, stream>>>(Yb, Wb + 3ull * DIMSZ * DIMSZ, out, 4096, 1024, 1024);
}